// Round 4
// baseline (250.323 us; speedup 1.0000x reference)
//
#include <hip/hip_runtime.h>

// Circle (ball) projection: out = center + (x-center) * min(1, R/max(||x-center||,1e-12))
// B = 8,388,608 points, 3 fp32 coords, AoS [B,3].
//
// R5 = R4 (register-resident AoS streaming, no LDS) + manual x4 unroll with
// BATCHED loads.
//
// R4 post-mortem: 4 structures (naive stride-3 / LDS+barriers / wave-private
// pipelined LDS / pure-register streaming) all converge at 93-99 us ~= 3.2 TB/s
// app traffic vs 6.29 TB/s for the m13 float4 copy. Common factor exposed by
// R4's VGPR_Count=12: the compiler did NOT unroll the grid-stride loop — each
// wave issues 2 loads, waits vmcnt(0) (first FLOP needs both), computes ~60
// VALU ops, stores, repeats. Successive chunks of one wave have ZERO memory
// overlap; per-wave MLP = 2 KB.
//
// Fix: process 4 chunks per iteration, issuing all 8 global_load_dwordx4
// before any compute. Chunk 0's compute waits at vmcnt(6); chunks 1-3's loads
// fly under chunk 0-2's compute+store. Per-wave in-flight: 2 KB -> 8 KB.
// 12 chunks/wave = exactly 3 unrolled iterations (99,864 = 8192*12 + 1560;
// 1560 waves run a single-chunk epilogue).
//
// Chunking (from R4): 63 float4 = 252 floats = 84 points exactly, so chunks
// are point-aligned; lane l's float4 phase = l % 3. Split points span lanes
// (l, l+1) of the same wave -> one __shfl_up + one __shfl_down completes
// |d|^2. Lane 63 idles (1.6% waste, no duplicate traffic). No LDS.

#define RADIUS 1.0f

__device__ __forceinline__ void chunk_compute_store(
    const float4 x4, const float4 c4,
    const bool active, const bool ph0, const bool ph2, const bool b1,
    float4* __restrict__ ov, const long f)
{
    const float d0 = x4.x - c4.x, d1 = x4.y - c4.y;
    const float d2 = x4.z - c4.z, d3 = x4.w - c4.w;
    const float q0 = d0*d0, q1 = d1*d1, q2 = d2*d2, q3 = d3*d3;

    // Own-floats contribution to this lane's head point / tail point.
    const float hp = q0 + (b1   ? q1 : 0.0f) + (ph0 ? q2 : 0.0f);
    const float tp = q3 + (!ph0 ? q2 : 0.0f) + (ph2 ? q1 : 0.0f);

    // Cross-lane completion of split points (neighbor lanes only).
    const float hp_next = __shfl_down(hp, 1, 64);  // from lane l+1
    const float tp_prev = __shfl_up(tp, 1, 64);    // from lane l-1

    const float n2h = hp + (ph0 ? 0.0f : tp_prev); // full |d|^2, head pt
    const float n2t = tp + (ph2 ? 0.0f : hp_next); // full |d|^2, tail pt

    // min(1, R/max(n,1e-12)) == min(1, R*rsqrt(max(n2,1e-24)))
    const float sh = fminf(1.0f, RADIUS * rsqrtf(fmaxf(n2h, 1e-24f)));
    const float st = fminf(1.0f, RADIUS * rsqrtf(fmaxf(n2t, 1e-24f)));

    // Component -> point mapping: comp0 always head, comp3 always tail,
    // comp1 head iff phase<2, comp2 head iff phase==0.
    const float s1 = b1  ? sh : st;
    const float s2 = ph0 ? sh : st;

    if (active) {
        ov[f] = make_float4(c4.x + d0*sh, c4.y + d1*s1,
                            c4.z + d2*s2, c4.w + d3*st);
    }
}

__global__ __launch_bounds__(256, 8) void circle_proj_stream4(
    const float4* __restrict__ xv,
    const float4* __restrict__ cv,
    float4* __restrict__ ov,
    long nchunks)   // number of 63-float4 (84-point) chunks
{
    const int wid   = threadIdx.x >> 6;
    const int lane  = threadIdx.x & 63;
    const int phase = lane % 3;            // f4 index mod 3 (63 ≡ 0 mod 3)
    const bool ph0  = (phase == 0);
    const bool ph2  = (phase == 2);
    const bool b1   = (phase < 2);         // comp1 belongs to head point
    const bool active = (lane < 63);

    const long nw = (long)gridDim.x * 4;   // total waves (8192 at full grid)
    long ch = (long)blockIdx.x * 4 + wid;

    // Main loop: 4 chunks per iteration, all 8 loads batched before compute.
    for (; ch + 3*nw < nchunks; ch += 4*nw) {
        float4 xx[4], cc[4];
#pragma unroll
        for (int j = 0; j < 4; ++j) {
            xx[j] = make_float4(0.f, 0.f, 0.f, 0.f);
            cc[j] = make_float4(0.f, 0.f, 0.f, 0.f);
        }
        if (active) {
#pragma unroll
            for (int j = 0; j < 4; ++j) {
                const long f = (ch + j*nw) * 63 + lane;
                xx[j] = xv[f];
                cc[j] = cv[f];
            }
        }
#pragma unroll
        for (int j = 0; j < 4; ++j) {
            chunk_compute_store(xx[j], cc[j], active, ph0, ph2, b1,
                                ov, (ch + j*nw) * 63 + lane);
        }
    }

    // Epilogue: up to 3 leftover single chunks.
    for (; ch < nchunks; ch += nw) {
        float4 x4 = make_float4(0.f, 0.f, 0.f, 0.f);
        float4 c4 = make_float4(0.f, 0.f, 0.f, 0.f);
        const long f = ch * 63 + lane;
        if (active) { x4 = xv[f]; c4 = cv[f]; }
        chunk_compute_store(x4, c4, active, ph0, ph2, b1, ov, f);
    }
}

// Tail: one thread per point, scalar loads. Covers the last (nf4 % 63) float4s
// at point granularity (32 points at B=8M).
__global__ __launch_bounds__(256) void circle_proj_tail(
    const float* __restrict__ x,
    const float* __restrict__ c,
    float* __restrict__ o,
    long start_pt, long npts)
{
    long p = start_pt + blockIdx.x * blockDim.x + threadIdx.x;
    if (p >= npts) return;
    float dx = x[3*p+0] - c[3*p+0];
    float dy = x[3*p+1] - c[3*p+1];
    float dz = x[3*p+2] - c[3*p+2];
    float n = sqrtf(dx*dx + dy*dy + dz*dz);
    float scale = fminf(1.0f, RADIUS / fmaxf(n, 1e-12f));
    o[3*p+0] = c[3*p+0] + dx * scale;
    o[3*p+1] = c[3*p+1] + dy * scale;
    o[3*p+2] = c[3*p+2] + dz * scale;
}

extern "C" void kernel_launch(void* const* d_in, const int* in_sizes, int n_in,
                              void* d_out, int out_size, void* d_ws, size_t ws_size,
                              hipStream_t stream) {
    const float* x = (const float*)d_in[0];   // [B,3] fp32
    const float* c = (const float*)d_in[1];   // [B,3] fp32
    float* out = (float*)d_out;

    long total_floats = in_sizes[0];          // B*3 = 25,165,824
    long nf4 = total_floats / 4;              // 6,291,456
    long nchunks = nf4 / 63;                  // 99,864 chunks of 84 points

    if (nchunks > 0) {
        long blocks = (nchunks + 3) / 4;
        if (blocks > 2048) blocks = 2048;     // 8 blocks/CU; 12 chunks/wave
        circle_proj_stream4<<<(int)blocks, 256, 0, stream>>>(
            (const float4*)x, (const float4*)c, (float4*)out, nchunks);
    }

    long pts_done = nchunks * 84;             // chunks are point-aligned
    long npts = total_floats / 3;
    if (pts_done < npts) {
        long rem = npts - pts_done;
        int grid = (int)((rem + 255) / 256);
        circle_proj_tail<<<grid, 256, 0, stream>>>(x, c, out, pts_done, npts);
    }
}

// Round 6
// 231.806 us; speedup vs baseline: 1.0799x; 1.0799x over previous
//
#include <hip/hip_runtime.h>

// Circle (ball) projection: out = center + (x-center) * min(1, R/max(||x-center||,1e-12))
// B = 8,388,608 points, 3 fp32 coords, AoS [B,3].
//
// R7 = R6 resubmitted verbatim (R6's bench never ran: the MI355X container
// failed twice before compile/test — no data was produced either way).
//
// R6 rationale: R4 structure (register-resident AoS, no LDS, contiguous
// per-wave chunks) + two last untested levers:
//   1. NONTEMPORAL LOADS: reads are single-use; nt bit changes L1/L2
//      allocation behavior — the only unperturbed part of the read path.
//      (nt stores measured -6% in R3; nt LOADS never tried. Stores stay plain.)
//   2. MLP WITH LOCALITY: R5's x4 unroll strided chunks 8.25 MB apart and
//      REGRESSED (94->100 us, FETCH +7%). Here each wave batches 2 ADJACENT
//      63-float4 chunks (contiguous 2KB window per array): 2x R4's in-flight
//      bytes at R4's locality.
//
// Scoreboard: 5 structures (naive stride-3 / LDS+barriers / wave-private
// pipelined / register streaming / strided-MLP) all pin at 93-100 us
// (~3.2 TB/s app) vs 6.29 TB/s copy. Replay passes show duration identical
// whether reads hit L3 or HBM. If R7 also lands 93-100 us, the 2R+1W mix is
// platform-capped and this is the roofline.
//
// Chunking (verified in R4/R5): 63 float4 = 84 points exactly; lane l's f4
// phase = l % 3; split points span lanes (l, l+1) -> one __shfl_up + one
// __shfl_down completes |d|^2. Pair offset 63 f4 keeps the same phase
// (63 ≡ 0 mod 3). Lane 63 idles (1.6% waste).

#define RADIUS 1.0f

typedef float f32x4 __attribute__((ext_vector_type(4)));

__device__ __forceinline__ float4 ntload4(const float4* p) {
    f32x4 v = __builtin_nontemporal_load((const f32x4*)p);
    return make_float4(v.x, v.y, v.z, v.w);
}

__device__ __forceinline__ void chunk_compute_store(
    const float4 x4, const float4 c4,
    const bool active, const bool ph0, const bool ph2, const bool b1,
    float4* __restrict__ ov, const long f)
{
    const float d0 = x4.x - c4.x, d1 = x4.y - c4.y;
    const float d2 = x4.z - c4.z, d3 = x4.w - c4.w;
    const float q0 = d0*d0, q1 = d1*d1, q2 = d2*d2, q3 = d3*d3;

    // Own-floats contribution to this lane's head point / tail point.
    const float hp = q0 + (b1   ? q1 : 0.0f) + (ph0 ? q2 : 0.0f);
    const float tp = q3 + (!ph0 ? q2 : 0.0f) + (ph2 ? q1 : 0.0f);

    // Cross-lane completion of split points (neighbor lanes only).
    const float hp_next = __shfl_down(hp, 1, 64);  // from lane l+1
    const float tp_prev = __shfl_up(tp, 1, 64);    // from lane l-1

    const float n2h = hp + (ph0 ? 0.0f : tp_prev); // full |d|^2, head pt
    const float n2t = tp + (ph2 ? 0.0f : hp_next); // full |d|^2, tail pt

    // min(1, R/max(n,1e-12)) == min(1, R*rsqrt(max(n2,1e-24)))
    const float sh = fminf(1.0f, RADIUS * rsqrtf(fmaxf(n2h, 1e-24f)));
    const float st = fminf(1.0f, RADIUS * rsqrtf(fmaxf(n2t, 1e-24f)));

    // Component -> point mapping: comp0 always head, comp3 always tail,
    // comp1 head iff phase<2, comp2 head iff phase==0.
    const float s1 = b1  ? sh : st;
    const float s2 = ph0 ? sh : st;

    if (active) {
        ov[f] = make_float4(c4.x + d0*sh, c4.y + d1*s1,
                            c4.z + d2*s2, c4.w + d3*st);
    }
}

__global__ __launch_bounds__(256, 8) void circle_proj_stream2c(
    const float4* __restrict__ xv,
    const float4* __restrict__ cv,
    float4* __restrict__ ov,
    long npairs)   // number of 126-float4 (168-point) pair-chunks
{
    const int wid   = threadIdx.x >> 6;
    const int lane  = threadIdx.x & 63;
    const int phase = lane % 3;            // f4 phase (126 ≡ 0 mod 3)
    const bool ph0  = (phase == 0);
    const bool ph2  = (phase == 2);
    const bool b1   = (phase < 2);         // comp1 belongs to head point
    const bool active = (lane < 63);

    const long nw = (long)gridDim.x * 4;   // total waves (8192 at full grid)

    for (long pc = (long)blockIdx.x * 4 + wid; pc < npairs; pc += nw) {
        const long f = pc * 126 + lane;    // chunk A; chunk B at f + 63

        float4 xa = make_float4(0.f,0.f,0.f,0.f), ca = xa;
        float4 xb = xa, cb = xa;
        if (active) {
            // Batched, ordered so chunk A's pair completes first (vmcnt(2)
            // leaves B's loads in flight under A's compute+store).
            xa = ntload4(&xv[f]);
            ca = ntload4(&cv[f]);
            xb = ntload4(&xv[f + 63]);
            cb = ntload4(&cv[f + 63]);
        }

        chunk_compute_store(xa, ca, active, ph0, ph2, b1, ov, f);
        chunk_compute_store(xb, cb, active, ph0, ph2, b1, ov, f + 63);
    }
}

// Tail: one thread per point, scalar loads. Covers everything past the last
// full pair-chunk (32 points at B=8M; bounded by ~200 in general).
__global__ __launch_bounds__(256) void circle_proj_tail(
    const float* __restrict__ x,
    const float* __restrict__ c,
    float* __restrict__ o,
    long start_pt, long npts)
{
    long p = start_pt + blockIdx.x * blockDim.x + threadIdx.x;
    if (p >= npts) return;
    float dx = x[3*p+0] - c[3*p+0];
    float dy = x[3*p+1] - c[3*p+1];
    float dz = x[3*p+2] - c[3*p+2];
    float n = sqrtf(dx*dx + dy*dy + dz*dz);
    float scale = fminf(1.0f, RADIUS / fmaxf(n, 1e-12f));
    o[3*p+0] = c[3*p+0] + dx * scale;
    o[3*p+1] = c[3*p+1] + dy * scale;
    o[3*p+2] = c[3*p+2] + dz * scale;
}

extern "C" void kernel_launch(void* const* d_in, const int* in_sizes, int n_in,
                              void* d_out, int out_size, void* d_ws, size_t ws_size,
                              hipStream_t stream) {
    const float* x = (const float*)d_in[0];   // [B,3] fp32
    const float* c = (const float*)d_in[1];   // [B,3] fp32
    float* out = (float*)d_out;

    long total_floats = in_sizes[0];          // B*3 = 25,165,824
    long nf4 = total_floats / 4;              // 6,291,456
    long npairs = nf4 / 126;                  // 49,932 pair-chunks (168 pts)

    if (npairs > 0) {
        long blocks = (npairs + 3) / 4;
        if (blocks > 2048) blocks = 2048;     // 8 blocks/CU, grid-stride
        circle_proj_stream2c<<<(int)blocks, 256, 0, stream>>>(
            (const float4*)x, (const float4*)c, (float4*)out, npairs);
    }

    long pts_done = npairs * 168;             // pair-chunks are point-aligned
    long npts = total_floats / 3;
    if (pts_done < npts) {
        long rem = npts - pts_done;
        int grid = (int)((rem + 255) / 256);
        circle_proj_tail<<<grid, 256, 0, stream>>>(x, c, out, pts_done, npts);
    }
}

// Round 7
// 231.234 us; speedup vs baseline: 1.0826x; 1.0025x over previous
//
#include <hip/hip_runtime.h>

// Circle (ball) projection: out = center + (x-center) * min(1, R/max(||x-center||,1e-12))
// B = 8,388,608 points, 3 fp32 coords, AoS [B,3].
//
// R8 = R7 (nt loads + adjacent-chunk MLP) with the MLP deepened 2 -> 4
// adjacent chunks per wave iteration.
//
// R7 post-mortem (first confirmed win): 94.4 -> 60.6 us/dispatch (-36%),
// hbm_gbps 2176 -> 3364, app traffic ~4.98 TB/s. The R0-R5 "3.2 TB/s wall"
// was per-wave in-flight starvation + read-path cache allocation, broken by
// nontemporal loads + batched ADJACENT chunks (R5's STRIDED batch regressed;
// adjacency is what made MLP pay). Riding the same gradient: 4 adjacent
// 63-float4 chunks per iteration = contiguous 4 KB window per array per
// wave, 8 nt loads in flight before any compute (vmcnt(6) at chunk A's
// compute). Stores stay plain (nt stores were -6% in R3's regime; the
// gradient lever with demonstrated slope is MLP).
//
// Chunking (verified R4-R7): 63 float4 = 84 points exactly; lane l's f4
// phase = l % 3; split points span lanes (l, l+1) -> one __shfl_up + one
// __shfl_down completes |d|^2. All sub-chunk offsets are multiples of 63
// (≡ 0 mod 3) -> same per-lane phase for all 4 chunks. Lane 63 idles
// (1.6% waste, zero duplicate traffic). No LDS anywhere.
//
// Quad = 252 float4 = 336 points. nf4 = 6,291,456 -> 24,966 quads exactly
// covering 8,388,576 points; 32-point remainder handled by the scalar tail.

#define RADIUS 1.0f

typedef float f32x4 __attribute__((ext_vector_type(4)));

__device__ __forceinline__ float4 ntload4(const float4* p) {
    f32x4 v = __builtin_nontemporal_load((const f32x4*)p);
    return make_float4(v.x, v.y, v.z, v.w);
}

__device__ __forceinline__ void chunk_compute_store(
    const float4 x4, const float4 c4,
    const bool active, const bool ph0, const bool ph2, const bool b1,
    float4* __restrict__ ov, const long f)
{
    const float d0 = x4.x - c4.x, d1 = x4.y - c4.y;
    const float d2 = x4.z - c4.z, d3 = x4.w - c4.w;
    const float q0 = d0*d0, q1 = d1*d1, q2 = d2*d2, q3 = d3*d3;

    // Own-floats contribution to this lane's head point / tail point.
    const float hp = q0 + (b1   ? q1 : 0.0f) + (ph0 ? q2 : 0.0f);
    const float tp = q3 + (!ph0 ? q2 : 0.0f) + (ph2 ? q1 : 0.0f);

    // Cross-lane completion of split points (neighbor lanes only).
    const float hp_next = __shfl_down(hp, 1, 64);  // from lane l+1
    const float tp_prev = __shfl_up(tp, 1, 64);    // from lane l-1

    const float n2h = hp + (ph0 ? 0.0f : tp_prev); // full |d|^2, head pt
    const float n2t = tp + (ph2 ? 0.0f : hp_next); // full |d|^2, tail pt

    // min(1, R/max(n,1e-12)) == min(1, R*rsqrt(max(n2,1e-24)))
    const float sh = fminf(1.0f, RADIUS * rsqrtf(fmaxf(n2h, 1e-24f)));
    const float st = fminf(1.0f, RADIUS * rsqrtf(fmaxf(n2t, 1e-24f)));

    // Component -> point mapping: comp0 always head, comp3 always tail,
    // comp1 head iff phase<2, comp2 head iff phase==0.
    const float s1 = b1  ? sh : st;
    const float s2 = ph0 ? sh : st;

    if (active) {
        ov[f] = make_float4(c4.x + d0*sh, c4.y + d1*s1,
                            c4.z + d2*s2, c4.w + d3*st);
    }
}

__global__ __launch_bounds__(256, 8) void circle_proj_stream4c(
    const float4* __restrict__ xv,
    const float4* __restrict__ cv,
    float4* __restrict__ ov,
    long nquads)   // number of 252-float4 (336-point) quad-chunks
{
    const int wid   = threadIdx.x >> 6;
    const int lane  = threadIdx.x & 63;
    const int phase = lane % 3;            // f4 phase (63k ≡ 0 mod 3)
    const bool ph0  = (phase == 0);
    const bool ph2  = (phase == 2);
    const bool b1   = (phase < 2);         // comp1 belongs to head point
    const bool active = (lane < 63);

    const long nw = (long)gridDim.x * 4;   // total waves (8192 at full grid)

    for (long qc = (long)blockIdx.x * 4 + wid; qc < nquads; qc += nw) {
        const long f = qc * 252 + lane;    // chunks at f, f+63, f+126, f+189

        float4 xa = make_float4(0.f,0.f,0.f,0.f), ca = xa;
        float4 xb = xa, cb = xa, xc = xa, cc = xa, xd = xa, cd = xa;
        if (active) {
            // All 8 nt loads issued before any compute; ordered so chunk A
            // completes first (its compute waits at vmcnt(6), leaving B/C/D's
            // loads in flight under A..C's compute+store).
            xa = ntload4(&xv[f]);
            ca = ntload4(&cv[f]);
            xb = ntload4(&xv[f +  63]);
            cb = ntload4(&cv[f +  63]);
            xc = ntload4(&xv[f + 126]);
            cc = ntload4(&cv[f + 126]);
            xd = ntload4(&xv[f + 189]);
            cd = ntload4(&cv[f + 189]);
        }

        chunk_compute_store(xa, ca, active, ph0, ph2, b1, ov, f);
        chunk_compute_store(xb, cb, active, ph0, ph2, b1, ov, f +  63);
        chunk_compute_store(xc, cc, active, ph0, ph2, b1, ov, f + 126);
        chunk_compute_store(xd, cd, active, ph0, ph2, b1, ov, f + 189);
    }
}

// Tail: one thread per point, scalar loads. Covers everything past the last
// full quad-chunk (32 points at B=8M; bounded by ~340 in general).
__global__ __launch_bounds__(256) void circle_proj_tail(
    const float* __restrict__ x,
    const float* __restrict__ c,
    float* __restrict__ o,
    long start_pt, long npts)
{
    long p = start_pt + blockIdx.x * blockDim.x + threadIdx.x;
    if (p >= npts) return;
    float dx = x[3*p+0] - c[3*p+0];
    float dy = x[3*p+1] - c[3*p+1];
    float dz = x[3*p+2] - c[3*p+2];
    float n = sqrtf(dx*dx + dy*dy + dz*dz);
    float scale = fminf(1.0f, RADIUS / fmaxf(n, 1e-12f));
    o[3*p+0] = c[3*p+0] + dx * scale;
    o[3*p+1] = c[3*p+1] + dy * scale;
    o[3*p+2] = c[3*p+2] + dz * scale;
}

extern "C" void kernel_launch(void* const* d_in, const int* in_sizes, int n_in,
                              void* d_out, int out_size, void* d_ws, size_t ws_size,
                              hipStream_t stream) {
    const float* x = (const float*)d_in[0];   // [B,3] fp32
    const float* c = (const float*)d_in[1];   // [B,3] fp32
    float* out = (float*)d_out;

    long total_floats = in_sizes[0];          // B*3 = 25,165,824
    long nf4 = total_floats / 4;              // 6,291,456
    long nquads = nf4 / 252;                  // 24,966 quad-chunks (336 pts)

    if (nquads > 0) {
        long blocks = (nquads + 3) / 4;
        if (blocks > 2048) blocks = 2048;     // 8 blocks/CU, grid-stride
        circle_proj_stream4c<<<(int)blocks, 256, 0, stream>>>(
            (const float4*)x, (const float4*)c, (float4*)out, nquads);
    }

    long pts_done = nquads * 336;             // quad-chunks are point-aligned
    long npts = total_floats / 3;
    if (pts_done < npts) {
        long rem = npts - pts_done;
        int grid = (int)((rem + 255) / 256);
        circle_proj_tail<<<grid, 256, 0, stream>>>(x, c, out, pts_done, npts);
    }
}